// Round 5
// baseline (370.254 us; speedup 1.0000x reference)
//
#include <hip/hip_runtime.h>

// GCN forward: 3x (GCNConv improved + ReLU) + GCNConv(out, 1 feature)
// N=50000 nodes, E=1.6M edges, H=64 features. All f32.
// CSR built via atomic-free MSD counting sort (LDS atomics only).
// Agg kernels: per-edge meta pre-packed as {src, di[src]} (one 8B sequential
// load/edge), unroll-8 with manual prefetch -> 8 row-gathers in flight.

#define HF 64
#define EPB 16384         // edges per block in passes A/B

// ---------------- pass A: coarse histogram (bucket = dst>>8) ----------------
__global__ __launch_bounds__(256) void pA_hist(const int* __restrict__ dst,
                                               int* __restrict__ histT, int E, int G) {
    __shared__ int h[256];
    int g = blockIdx.x, t = threadIdx.x;
    h[t] = 0;
    __syncthreads();
    int beg = g * EPB, end = min(beg + EPB, E);
    for (int i = beg + t; i < end; i += 256) atomicAdd(&h[dst[i] >> 8], 1);
    __syncthreads();
    histT[t * G + g] = h[t];
}

// ---------------- scan: linear exclusive scan of histT (bucket-major) ----------------
#define ST 1024
__global__ __launch_bounds__(ST) void pScan(int* __restrict__ hist,
                                            int* __restrict__ coarse, int G, int E) {
    __shared__ int sd[ST];
    int t = threadIdx.x;
    int M = 256 * G;
    int chunk = (M + ST - 1) / ST;
    int beg = t * chunk, end = min(beg + chunk, M);
    int s = 0;
    for (int fi = beg; fi < end; ++fi) s += hist[fi];
    sd[t] = s;
    __syncthreads();
    for (int o = 1; o < ST; o <<= 1) {
        int u = (t >= o) ? sd[t - o] : 0;
        __syncthreads();
        sd[t] += u;
        __syncthreads();
    }
    int run = sd[t] - s;
    for (int fi = beg; fi < end; ++fi) {
        int v = hist[fi];
        hist[fi] = run;
        if (fi % G == 0) coarse[fi / G] = run;
        run += v;
    }
    if (t == ST - 1) coarse[256] = E;
}

// ---------------- pass B: coarse scatter (LDS cursors) ----------------
__global__ __launch_bounds__(256) void pB_scatter(const int* __restrict__ src,
                                                  const int* __restrict__ dst,
                                                  const int* __restrict__ histT,
                                                  unsigned int* __restrict__ tmp,
                                                  int E, int G) {
    __shared__ int cur[256];
    int g = blockIdx.x, t = threadIdx.x;
    cur[t] = histT[t * G + g];
    __syncthreads();
    int beg = g * EPB, end = min(beg + EPB, E);
    for (int i = beg + t; i < end; i += 256) {
        int d = dst[i], s = src[i];
        int pos = atomicAdd(&cur[d >> 8], 1);
        tmp[pos] = ((unsigned int)(d & 255) << 16) | (unsigned int)(s & 0xFFFF);
    }
}

// ---------------- pass C: per-bucket fine counting sort + CSR metadata ----------------
__global__ __launch_bounds__(256) void pC_build(const unsigned int* __restrict__ tmp,
                                                const int* __restrict__ coarse,
                                                ushort* __restrict__ csrs,
                                                int* __restrict__ offs,
                                                float* __restrict__ di,
                                                float* __restrict__ dp,
                                                int n, int E, int NB) {
    __shared__ int hist[256];
    __shared__ int cur[256];
    __shared__ int scanbuf[256];
    int b = blockIdx.x, t = threadIdx.x;
    int beg = coarse[b], end = coarse[b + 1];
    hist[t] = 0;
    __syncthreads();
    for (int i = beg + t; i < end; i += 256) atomicAdd(&hist[tmp[i] >> 16], 1);
    __syncthreads();
    int v = hist[t];
    scanbuf[t] = v;
    __syncthreads();
    for (int o = 1; o < 256; o <<= 1) {
        int u = (t >= o) ? scanbuf[t - o] : 0;
        __syncthreads();
        scanbuf[t] += u;
        __syncthreads();
    }
    int excl = scanbuf[t] - v;
    cur[t] = beg + excl;
    int d = (b << 8) + t;
    if (d < n) {
        offs[d] = beg + excl;
        float df = (float)v;
        di[d] = rsqrtf(df + 2.0f);   // improved=True: self-loop weight 2
        dp[d] = rsqrtf(df + 1.0f);   // output layer: improved=False
    }
    if (b == NB - 1 && t == 0) offs[n] = E;
    __syncthreads();
    for (int i = beg + t; i < end; i += 256) {
        unsigned int e = tmp[i];
        int pos = atomicAdd(&cur[e >> 16], 1);
        csrs[pos] = (ushort)(e & 0xFFFFu);
    }
}

// ---------------- pack per-edge meta: {src, di[src]} (8B, loaded sequentially) ----
__global__ void k_pack(const ushort* __restrict__ csrs, const float* __restrict__ di,
                       uint2* __restrict__ csrp, int E) {
    int i = blockIdx.x * blockDim.x + threadIdx.x;
    if (i < E) {
        int s = csrs[i];
        csrp[i] = make_uint2((unsigned)s, __float_as_uint(di[s]));
    }
}

// ---------------- dense GEMM: C[n,64] = A[n,64] @ W[64,64] ----------------
#define GM_BN 128
__global__ __launch_bounds__(256) void k_gemm(const float* __restrict__ A,
                                              const float* __restrict__ W,
                                              float* __restrict__ C, int n) {
    __shared__ float xT[64][132];
    __shared__ float Wl[64][64];
    int tid = threadIdx.x;
    int nb = blockIdx.x * GM_BN;

    for (int r = 0; r < 4; ++r) {
        int q = tid + 256 * r;
        int row = q >> 4, c4 = (q & 15) << 2;
        *(float4*)&Wl[row][c4] = *(const float4*)&W[row * 64 + c4];
    }
    for (int r = 0; r < 8; ++r) {
        int q = tid + 256 * r;
        int nl = q >> 4, k0 = (q & 15) << 2;
        float4 v = make_float4(0.f, 0.f, 0.f, 0.f);
        if (nb + nl < n) v = *(const float4*)&A[(size_t)(nb + nl) * HF + k0];
        xT[k0 + 0][nl] = v.x; xT[k0 + 1][nl] = v.y;
        xT[k0 + 2][nl] = v.z; xT[k0 + 3][nl] = v.w;
    }
    __syncthreads();

    int tx = tid & 7;
    int ty = tid >> 3;
    int f0 = tx * 8, n0 = ty * 4;
    float acc[4][8];
#pragma unroll
    for (int i = 0; i < 4; ++i)
#pragma unroll
        for (int j = 0; j < 8; ++j) acc[i][j] = 0.f;

#pragma unroll 4
    for (int k = 0; k < 64; ++k) {
        float4 xa = *(float4*)&xT[k][n0];
        float4 wa = *(float4*)&Wl[k][f0];
        float4 wb = *(float4*)&Wl[k][f0 + 4];
        float xs[4] = {xa.x, xa.y, xa.z, xa.w};
        float wsv[8] = {wa.x, wa.y, wa.z, wa.w, wb.x, wb.y, wb.z, wb.w};
#pragma unroll
        for (int i = 0; i < 4; ++i)
#pragma unroll
            for (int j = 0; j < 8; ++j) acc[i][j] += xs[i] * wsv[j];
    }

#pragma unroll
    for (int i = 0; i < 4; ++i) {
        int nn = nb + n0 + i;
        if (nn < n) {
            *(float4*)&C[(size_t)nn * HF + f0] =
                make_float4(acc[i][0], acc[i][1], acc[i][2], acc[i][3]);
            *(float4*)&C[(size_t)nn * HF + f0 + 4] =
                make_float4(acc[i][4], acc[i][5], acc[i][6], acc[i][7]);
        }
    }
}

// ---------------- agg body: 8-deep pipelined gather, shared by both agg kernels ----
__device__ __forceinline__ float agg_edges(const float* __restrict__ P,
                                           const uint2* __restrict__ cp,
                                           int deg, int f) {
    float acc0 = 0.f, acc1 = 0.f;
    int nfull = deg >> 3;
    if (nfull > 0) {
        uint2 m0 = cp[0], m1 = cp[1], m2 = cp[2], m3 = cp[3];
        uint2 m4 = cp[4], m5 = cp[5], m6 = cp[6], m7 = cp[7];
        for (int c = 0; c < nfull; ++c) {
            uint2 t0, t1, t2, t3, t4, t5, t6, t7;
            bool more = (c + 1 < nfull);
            if (more) {
                const uint2* nx = cp + ((c + 1) << 3);
                t0 = nx[0]; t1 = nx[1]; t2 = nx[2]; t3 = nx[3];
                t4 = nx[4]; t5 = nx[5]; t6 = nx[6]; t7 = nx[7];
            }
            float p0 = P[(size_t)m0.x * HF + f];
            float p1 = P[(size_t)m1.x * HF + f];
            float p2 = P[(size_t)m2.x * HF + f];
            float p3 = P[(size_t)m3.x * HF + f];
            float p4 = P[(size_t)m4.x * HF + f];
            float p5 = P[(size_t)m5.x * HF + f];
            float p6 = P[(size_t)m6.x * HF + f];
            float p7 = P[(size_t)m7.x * HF + f];
            acc0 += __uint_as_float(m0.y) * p0;
            acc1 += __uint_as_float(m1.y) * p1;
            acc0 += __uint_as_float(m2.y) * p2;
            acc1 += __uint_as_float(m3.y) * p3;
            acc0 += __uint_as_float(m4.y) * p4;
            acc1 += __uint_as_float(m5.y) * p5;
            acc0 += __uint_as_float(m6.y) * p6;
            acc1 += __uint_as_float(m7.y) * p7;
            if (more) {
                m0 = t0; m1 = t1; m2 = t2; m3 = t3;
                m4 = t4; m5 = t5; m6 = t6; m7 = t7;
            }
        }
    }
    for (int i = nfull << 3; i < deg; ++i) {
        uint2 q = cp[i];
        acc0 += __uint_as_float(q.y) * P[(size_t)q.x * HF + f];
    }
    return acc0 + acc1;
}

// ---------------- sparse aggregation: one wave per node, lane=feature ----------------
__global__ void k_agg(const float* __restrict__ P, const int* __restrict__ offs,
                      const uint2* __restrict__ csrp, const float* __restrict__ di,
                      const float* __restrict__ bias, float* __restrict__ out,
                      int n, float fill) {
    int wid = (blockIdx.x * blockDim.x + threadIdx.x) >> 6;
    int f = threadIdx.x & 63;
    if (wid >= n) return;
    int beg = offs[wid], end = offs[wid + 1];
    float dw = di[wid];
    float acc = agg_edges(P, csrp + beg, end - beg, f);
    acc *= dw;
    acc += fill * dw * dw * P[(size_t)wid * HF + f];
    acc += bias[f];
    acc = fmaxf(acc, 0.f);
    out[(size_t)wid * HF + f] = acc;
}

// ---------------- layer-3 agg fused with output projection ----------------
__global__ void k_agg_final(const float* __restrict__ P, const int* __restrict__ offs,
                            const uint2* __restrict__ csrp, const float* __restrict__ di,
                            const float* __restrict__ bias, const float* __restrict__ Wout,
                            const float* __restrict__ dp, float* __restrict__ z2, int n) {
    int wid = (blockIdx.x * blockDim.x + threadIdx.x) >> 6;
    int f = threadIdx.x & 63;
    if (wid >= n) return;
    int beg = offs[wid], end = offs[wid + 1];
    float dw = di[wid];
    float acc = agg_edges(P, csrp + beg, end - beg, f);
    acc *= dw;
    acc += 2.0f * dw * dw * P[(size_t)wid * HF + f];
    acc += bias[f];
    acc = fmaxf(acc, 0.f);
    float v = acc * Wout[f];
#pragma unroll
    for (int o = 32; o > 0; o >>= 1) v += __shfl_down(v, o, 64);
    if (f == 0) z2[wid] = v * dp[wid];
}

// out[n] = dp[n] * (sum_e z2[src] + z2[n]) + b_out
__global__ void k_out(const float* __restrict__ z2, const int* __restrict__ offs,
                      const ushort* __restrict__ csrs, const float* __restrict__ dp,
                      const float* __restrict__ bout, float* __restrict__ out, int n) {
    int i = blockIdx.x * blockDim.x + threadIdx.x;
    if (i >= n) return;
    int beg = offs[i], end = offs[i + 1];
    float acc = 0.f;
    for (int e = beg; e < end; ++e) acc += z2[csrs[e]];
    out[i] = dp[i] * (acc + z2[i]) + bout[0];
}

extern "C" void kernel_launch(void* const* d_in, const int* in_sizes, int n_in,
                              void* d_out, int out_size, void* d_ws, size_t ws_size,
                              hipStream_t stream) {
    const float* x    = (const float*)d_in[0];
    const int*   ei   = (const int*)d_in[1];
    const float* W_in = (const float*)d_in[2];
    const float* b_in = (const float*)d_in[3];
    const float* W_h1 = (const float*)d_in[4];
    const float* b_h1 = (const float*)d_in[5];
    const float* W_h2 = (const float*)d_in[6];
    const float* b_h2 = (const float*)d_in[7];
    const float* W_out= (const float*)d_in[8];
    const float* b_out= (const float*)d_in[9];
    float* out = (float*)d_out;

    const int n = in_sizes[0] / HF;        // 50000 (< 65536: ushort CSR ok)
    const int E = in_sizes[1] / 2;         // 1.6M
    const int* src = ei;
    const int* dst = ei + E;

    const int G  = (E + EPB - 1) / EPB;
    const int NB = (n + 255) >> 8;

    char* ws = (char*)d_ws;
    size_t o = 0;
    auto alloc = [&](size_t bytes) -> void* {
        void* p = ws + o;
        o += (bytes + 255) & ~(size_t)255;
        return p;
    };
    int*          offs   = (int*)   alloc((size_t)(n + 1) * 4);
    float*        di     = (float*) alloc((size_t)n * 4);
    float*        dp     = (float*) alloc((size_t)n * 4);
    ushort*       csrs   = (ushort*)alloc((size_t)E * 2);
    uint2*        csrp   = (uint2*) alloc((size_t)E * 8);
    unsigned int* tmp    = (unsigned int*)alloc((size_t)E * 4);
    int*          histT  = (int*)   alloc((size_t)G * 256 * 4);
    int*          coarse = (int*)   alloc(257 * 4);
    float*        hW     = (float*) alloc((size_t)n * HF * 4);
    float*        hA     = (float*) alloc((size_t)n * HF * 4);
    float*        hB     = (float*) alloc((size_t)n * HF * 4);
    float*        z2     = (float*) alloc((size_t)n * 4);

    const int TB = 256;
    int gbN = (n + TB - 1) / TB;
    int gbE = (E + TB - 1) / TB;
    int gbW = (n * 64 + TB - 1) / TB;
    int gbG = (n + GM_BN - 1) / GM_BN;

    // ---- CSR build (atomic-free, LDS atomics only) ----
    pA_hist   <<<G,  TB, 0, stream>>>(dst, histT, E, G);
    pScan     <<<1,  ST, 0, stream>>>(histT, coarse, G, E);
    pB_scatter<<<G,  TB, 0, stream>>>(src, dst, histT, tmp, E, G);
    pC_build  <<<NB, TB, 0, stream>>>(tmp, coarse, csrs, offs, di, dp, n, E, NB);
    k_pack    <<<gbE, TB, 0, stream>>>(csrs, di, csrp, E);

    // ---- layer 1 ----
    k_gemm<<<gbG, TB, 0, stream>>>(x, W_in, hW, n);
    k_agg<<<gbW, TB, 0, stream>>>(hW, offs, csrp, di, b_in, hA, n, 2.0f);
    // ---- layer 2 ----
    k_gemm<<<gbG, TB, 0, stream>>>(hA, W_h1, hW, n);
    k_agg<<<gbW, TB, 0, stream>>>(hW, offs, csrp, di, b_h1, hB, n, 2.0f);
    // ---- layer 3 (agg fused with output projection) ----
    k_gemm<<<gbG, TB, 0, stream>>>(hB, W_h2, hW, n);
    k_agg_final<<<gbW, TB, 0, stream>>>(hW, offs, csrp, di, b_h2, W_out, dp, z2, n);
    // ---- output layer ----
    k_out<<<gbN, TB, 0, stream>>>(z2, offs, csrs, dp, b_out, out, n);
}

// Round 6
// 326.901 us; speedup vs baseline: 1.1326x; 1.1326x over previous
//
#include <hip/hip_runtime.h>
#include <hip/hip_fp16.h>

// GCN forward: 3x (GCNConv improved + ReLU) + GCNConv(out, 1 feature)
// N=50000 nodes, E=1.6M edges, H=64 features.
// CSR built via atomic-free MSD counting sort (LDS atomics only).
// Gather table (GEMM outputs) stored fp16: halves gather bytes AND L2-miss
// line count; 6.4MB table nearly fits per-XCD L2. All accumulation f32.
// Agg body: simple unroll-4 (R5's unroll-8 prefetch cost occupancy: 70->52%).

#define HF 64
#define EPB 16384         // edges per block in passes A/B

// ---------------- pass A: coarse histogram (bucket = dst>>8) ----------------
__global__ __launch_bounds__(256) void pA_hist(const int* __restrict__ dst,
                                               int* __restrict__ histT, int E, int G) {
    __shared__ int h[256];
    int g = blockIdx.x, t = threadIdx.x;
    h[t] = 0;
    __syncthreads();
    int beg = g * EPB, end = min(beg + EPB, E);
    for (int i = beg + t; i < end; i += 256) atomicAdd(&h[dst[i] >> 8], 1);
    __syncthreads();
    histT[t * G + g] = h[t];
}

// ---------------- scan: linear exclusive scan of histT (bucket-major) ----------------
#define ST 1024
__global__ __launch_bounds__(ST) void pScan(int* __restrict__ hist,
                                            int* __restrict__ coarse, int G, int E) {
    __shared__ int sd[ST];
    int t = threadIdx.x;
    int M = 256 * G;
    int chunk = (M + ST - 1) / ST;
    int beg = t * chunk, end = min(beg + chunk, M);
    int s = 0;
    for (int fi = beg; fi < end; ++fi) s += hist[fi];
    sd[t] = s;
    __syncthreads();
    for (int o = 1; o < ST; o <<= 1) {
        int u = (t >= o) ? sd[t - o] : 0;
        __syncthreads();
        sd[t] += u;
        __syncthreads();
    }
    int run = sd[t] - s;
    for (int fi = beg; fi < end; ++fi) {
        int v = hist[fi];
        hist[fi] = run;
        if (fi % G == 0) coarse[fi / G] = run;
        run += v;
    }
    if (t == ST - 1) coarse[256] = E;
}

// ---------------- pass B: coarse scatter (LDS cursors) ----------------
__global__ __launch_bounds__(256) void pB_scatter(const int* __restrict__ src,
                                                  const int* __restrict__ dst,
                                                  const int* __restrict__ histT,
                                                  unsigned int* __restrict__ tmp,
                                                  int E, int G) {
    __shared__ int cur[256];
    int g = blockIdx.x, t = threadIdx.x;
    cur[t] = histT[t * G + g];
    __syncthreads();
    int beg = g * EPB, end = min(beg + EPB, E);
    for (int i = beg + t; i < end; i += 256) {
        int d = dst[i], s = src[i];
        int pos = atomicAdd(&cur[d >> 8], 1);
        tmp[pos] = ((unsigned int)(d & 255) << 16) | (unsigned int)(s & 0xFFFF);
    }
}

// ---------------- pass C: per-bucket fine counting sort + CSR metadata ----------------
__global__ __launch_bounds__(256) void pC_build(const unsigned int* __restrict__ tmp,
                                                const int* __restrict__ coarse,
                                                ushort* __restrict__ csrs,
                                                int* __restrict__ offs,
                                                float* __restrict__ di,
                                                float* __restrict__ dp,
                                                int n, int E, int NB) {
    __shared__ int hist[256];
    __shared__ int cur[256];
    __shared__ int scanbuf[256];
    int b = blockIdx.x, t = threadIdx.x;
    int beg = coarse[b], end = coarse[b + 1];
    hist[t] = 0;
    __syncthreads();
    for (int i = beg + t; i < end; i += 256) atomicAdd(&hist[tmp[i] >> 16], 1);
    __syncthreads();
    int v = hist[t];
    scanbuf[t] = v;
    __syncthreads();
    for (int o = 1; o < 256; o <<= 1) {
        int u = (t >= o) ? scanbuf[t - o] : 0;
        __syncthreads();
        scanbuf[t] += u;
        __syncthreads();
    }
    int excl = scanbuf[t] - v;
    cur[t] = beg + excl;
    int d = (b << 8) + t;
    if (d < n) {
        offs[d] = beg + excl;
        float df = (float)v;
        di[d] = rsqrtf(df + 2.0f);   // improved=True: self-loop weight 2
        dp[d] = rsqrtf(df + 1.0f);   // output layer: improved=False
    }
    if (b == NB - 1 && t == 0) offs[n] = E;
    __syncthreads();
    for (int i = beg + t; i < end; i += 256) {
        unsigned int e = tmp[i];
        int pos = atomicAdd(&cur[e >> 16], 1);
        csrs[pos] = (ushort)(e & 0xFFFFu);
    }
}

// ---------------- pack per-edge meta: {src, di[src]} (8B sequential) ----------
__global__ void k_pack(const ushort* __restrict__ csrs, const float* __restrict__ di,
                       uint2* __restrict__ csrp, int E) {
    int i = blockIdx.x * blockDim.x + threadIdx.x;
    if (i < E) {
        int s = csrs[i];
        csrp[i] = make_uint2((unsigned)s, __float_as_uint(di[s]));
    }
}

// ---------------- dense GEMM: C[n,64] = A[n,64] @ W[64,64], C in fp16 --------
#define GM_BN 128
__global__ __launch_bounds__(256) void k_gemm(const float* __restrict__ A,
                                              const float* __restrict__ W,
                                              __half* __restrict__ C, int n) {
    __shared__ float xT[64][132];
    __shared__ float Wl[64][64];
    int tid = threadIdx.x;
    int nb = blockIdx.x * GM_BN;

    for (int r = 0; r < 4; ++r) {
        int q = tid + 256 * r;
        int row = q >> 4, c4 = (q & 15) << 2;
        *(float4*)&Wl[row][c4] = *(const float4*)&W[row * 64 + c4];
    }
    for (int r = 0; r < 8; ++r) {
        int q = tid + 256 * r;
        int nl = q >> 4, k0 = (q & 15) << 2;
        float4 v = make_float4(0.f, 0.f, 0.f, 0.f);
        if (nb + nl < n) v = *(const float4*)&A[(size_t)(nb + nl) * HF + k0];
        xT[k0 + 0][nl] = v.x; xT[k0 + 1][nl] = v.y;
        xT[k0 + 2][nl] = v.z; xT[k0 + 3][nl] = v.w;
    }
    __syncthreads();

    int tx = tid & 7;
    int ty = tid >> 3;
    int f0 = tx * 8, n0 = ty * 4;
    float acc[4][8];
#pragma unroll
    for (int i = 0; i < 4; ++i)
#pragma unroll
        for (int j = 0; j < 8; ++j) acc[i][j] = 0.f;

#pragma unroll 4
    for (int k = 0; k < 64; ++k) {
        float4 xa = *(float4*)&xT[k][n0];
        float4 wa = *(float4*)&Wl[k][f0];
        float4 wb = *(float4*)&Wl[k][f0 + 4];
        float xs[4] = {xa.x, xa.y, xa.z, xa.w};
        float wsv[8] = {wa.x, wa.y, wa.z, wa.w, wb.x, wb.y, wb.z, wb.w};
#pragma unroll
        for (int i = 0; i < 4; ++i)
#pragma unroll
            for (int j = 0; j < 8; ++j) acc[i][j] += xs[i] * wsv[j];
    }

#pragma unroll
    for (int i = 0; i < 4; ++i) {
        int nn = nb + n0 + i;
        if (nn < n) {
            union { __half h[8]; float4 f4; } u;
#pragma unroll
            for (int j = 0; j < 8; ++j) u.h[j] = __float2half(acc[i][j]);
            *(float4*)&C[(size_t)nn * HF + f0] = u.f4;
        }
    }
}

// ---------------- agg body: unroll-4 gather from fp16 table ------------------
__device__ __forceinline__ float agg_edges(const __half* __restrict__ P,
                                           const uint2* __restrict__ cp,
                                           int deg, int f) {
    float acc0 = 0.f, acc1 = 0.f;
    int e = 0;
    int end4 = deg & ~3;
    for (; e < end4; e += 4) {
        uint2 m0 = cp[e + 0], m1 = cp[e + 1], m2 = cp[e + 2], m3 = cp[e + 3];
        float p0 = __half2float(P[(size_t)m0.x * HF + f]);
        float p1 = __half2float(P[(size_t)m1.x * HF + f]);
        float p2 = __half2float(P[(size_t)m2.x * HF + f]);
        float p3 = __half2float(P[(size_t)m3.x * HF + f]);
        acc0 += __uint_as_float(m0.y) * p0;
        acc1 += __uint_as_float(m1.y) * p1;
        acc0 += __uint_as_float(m2.y) * p2;
        acc1 += __uint_as_float(m3.y) * p3;
    }
    for (; e < deg; ++e) {
        uint2 q = cp[e];
        acc0 += __uint_as_float(q.y) * __half2float(P[(size_t)q.x * HF + f]);
    }
    return acc0 + acc1;
}

// ---------------- sparse aggregation: one wave per node, lane=feature --------
__global__ void k_agg(const __half* __restrict__ P, const int* __restrict__ offs,
                      const uint2* __restrict__ csrp, const float* __restrict__ di,
                      const float* __restrict__ bias, float* __restrict__ out,
                      int n, float fill) {
    int wid = (blockIdx.x * blockDim.x + threadIdx.x) >> 6;
    int f = threadIdx.x & 63;
    if (wid >= n) return;
    int beg = offs[wid], end = offs[wid + 1];
    float dw = di[wid];
    float acc = agg_edges(P, csrp + beg, end - beg, f);
    acc *= dw;
    acc += fill * dw * dw * __half2float(P[(size_t)wid * HF + f]);
    acc += bias[f];
    acc = fmaxf(acc, 0.f);
    out[(size_t)wid * HF + f] = acc;
}

// ---------------- layer-3 agg fused with output projection -------------------
__global__ void k_agg_final(const __half* __restrict__ P, const int* __restrict__ offs,
                            const uint2* __restrict__ csrp, const float* __restrict__ di,
                            const float* __restrict__ bias, const float* __restrict__ Wout,
                            const float* __restrict__ dp, float* __restrict__ z2, int n) {
    int wid = (blockIdx.x * blockDim.x + threadIdx.x) >> 6;
    int f = threadIdx.x & 63;
    if (wid >= n) return;
    int beg = offs[wid], end = offs[wid + 1];
    float dw = di[wid];
    float acc = agg_edges(P, csrp + beg, end - beg, f);
    acc *= dw;
    acc += 2.0f * dw * dw * __half2float(P[(size_t)wid * HF + f]);
    acc += bias[f];
    acc = fmaxf(acc, 0.f);
    float v = acc * Wout[f];
#pragma unroll
    for (int o = 32; o > 0; o >>= 1) v += __shfl_down(v, o, 64);
    if (f == 0) z2[wid] = v * dp[wid];
}

// out[n] = dp[n] * (sum_e z2[src] + z2[n]) + b_out
__global__ void k_out(const float* __restrict__ z2, const int* __restrict__ offs,
                      const ushort* __restrict__ csrs, const float* __restrict__ dp,
                      const float* __restrict__ bout, float* __restrict__ out, int n) {
    int i = blockIdx.x * blockDim.x + threadIdx.x;
    if (i >= n) return;
    int beg = offs[i], end = offs[i + 1];
    float acc = 0.f;
    for (int e = beg; e < end; ++e) acc += z2[csrs[e]];
    out[i] = dp[i] * (acc + z2[i]) + bout[0];
}

extern "C" void kernel_launch(void* const* d_in, const int* in_sizes, int n_in,
                              void* d_out, int out_size, void* d_ws, size_t ws_size,
                              hipStream_t stream) {
    const float* x    = (const float*)d_in[0];
    const int*   ei   = (const int*)d_in[1];
    const float* W_in = (const float*)d_in[2];
    const float* b_in = (const float*)d_in[3];
    const float* W_h1 = (const float*)d_in[4];
    const float* b_h1 = (const float*)d_in[5];
    const float* W_h2 = (const float*)d_in[6];
    const float* b_h2 = (const float*)d_in[7];
    const float* W_out= (const float*)d_in[8];
    const float* b_out= (const float*)d_in[9];
    float* out = (float*)d_out;

    const int n = in_sizes[0] / HF;        // 50000 (< 65536: ushort CSR ok)
    const int E = in_sizes[1] / 2;         // 1.6M
    const int* src = ei;
    const int* dst = ei + E;

    const int G  = (E + EPB - 1) / EPB;
    const int NB = (n + 255) >> 8;

    char* ws = (char*)d_ws;
    size_t o = 0;
    auto alloc = [&](size_t bytes) -> void* {
        void* p = ws + o;
        o += (bytes + 255) & ~(size_t)255;
        return p;
    };
    int*          offs   = (int*)   alloc((size_t)(n + 1) * 4);
    float*        di     = (float*) alloc((size_t)n * 4);
    float*        dp     = (float*) alloc((size_t)n * 4);
    ushort*       csrs   = (ushort*)alloc((size_t)E * 2);
    uint2*        csrp   = (uint2*) alloc((size_t)E * 8);
    unsigned int* tmp    = (unsigned int*)alloc((size_t)E * 4);
    int*          histT  = (int*)   alloc((size_t)G * 256 * 4);
    int*          coarse = (int*)   alloc(257 * 4);
    __half*       hW     = (__half*)alloc((size_t)n * HF * 2);   // fp16 gather table
    float*        hA     = (float*) alloc((size_t)n * HF * 4);
    float*        hB     = (float*) alloc((size_t)n * HF * 4);
    float*        z2     = (float*) alloc((size_t)n * 4);

    const int TB = 256;
    int gbN = (n + TB - 1) / TB;
    int gbE = (E + TB - 1) / TB;
    int gbW = (n * 64 + TB - 1) / TB;
    int gbG = (n + GM_BN - 1) / GM_BN;

    // ---- CSR build (atomic-free, LDS atomics only) ----
    pA_hist   <<<G,  TB, 0, stream>>>(dst, histT, E, G);
    pScan     <<<1,  ST, 0, stream>>>(histT, coarse, G, E);
    pB_scatter<<<G,  TB, 0, stream>>>(src, dst, histT, tmp, E, G);
    pC_build  <<<NB, TB, 0, stream>>>(tmp, coarse, csrs, offs, di, dp, n, E, NB);
    k_pack    <<<gbE, TB, 0, stream>>>(csrs, di, csrp, E);

    // ---- layer 1 ----
    k_gemm<<<gbG, TB, 0, stream>>>(x, W_in, hW, n);
    k_agg<<<gbW, TB, 0, stream>>>(hW, offs, csrp, di, b_in, hA, n, 2.0f);
    // ---- layer 2 ----
    k_gemm<<<gbG, TB, 0, stream>>>(hA, W_h1, hW, n);
    k_agg<<<gbW, TB, 0, stream>>>(hW, offs, csrp, di, b_h1, hB, n, 2.0f);
    // ---- layer 3 (agg fused with output projection) ----
    k_gemm<<<gbG, TB, 0, stream>>>(hB, W_h2, hW, n);
    k_agg_final<<<gbW, TB, 0, stream>>>(hW, offs, csrp, di, b_h2, W_out, dp, z2, n);
    // ---- output layer ----
    k_out<<<gbN, TB, 0, stream>>>(z2, offs, csrs, dp, b_out, out, n);
}

// Round 7
// 305.080 us; speedup vs baseline: 1.2136x; 1.0715x over previous
//
#include <hip/hip_runtime.h>
#include <hip/hip_fp16.h>

// GCN forward: 3x (GCNConv improved + ReLU) + GCNConv(out, 1 feature)
// N=50000 nodes, E=1.6M edges, H=64 features.
// CSR via atomic-free MSD counting sort (LDS atomics only).
// Gather table = fp16 P'[s,f] = di[s]*(XW)[s,f]  (weight folded into table ->
// no per-edge weight data or FMA). Agg: half2 lanes, 2 edges per wave per
// load instruction, unroll-2 (4 rows in flight), f32 accumulation.

#define HF 64
#define EPB 16384         // edges per block in passes A/B

// ---------------- pass A: coarse histogram (bucket = dst>>8) ----------------
__global__ __launch_bounds__(256) void pA_hist(const int* __restrict__ dst,
                                               int* __restrict__ histT, int E, int G) {
    __shared__ int h[256];
    int g = blockIdx.x, t = threadIdx.x;
    h[t] = 0;
    __syncthreads();
    int beg = g * EPB, end = min(beg + EPB, E);
    for (int i = beg + t; i < end; i += 256) atomicAdd(&h[dst[i] >> 8], 1);
    __syncthreads();
    histT[t * G + g] = h[t];
}

// ---------------- scan: linear exclusive scan of histT (bucket-major) --------
#define ST 1024
__global__ __launch_bounds__(ST) void pScan(int* __restrict__ hist,
                                            int* __restrict__ coarse, int G, int E) {
    __shared__ int sd[ST];
    int t = threadIdx.x;
    int M = 256 * G;
    int chunk = (M + ST - 1) / ST;
    int beg = t * chunk, end = min(beg + chunk, M);
    int s = 0;
    for (int fi = beg; fi < end; ++fi) s += hist[fi];
    sd[t] = s;
    __syncthreads();
    for (int o = 1; o < ST; o <<= 1) {
        int u = (t >= o) ? sd[t - o] : 0;
        __syncthreads();
        sd[t] += u;
        __syncthreads();
    }
    int run = sd[t] - s;
    for (int fi = beg; fi < end; ++fi) {
        int v = hist[fi];
        hist[fi] = run;
        if (fi % G == 0) coarse[fi / G] = run;
        run += v;
    }
    if (t == ST - 1) coarse[256] = E;
}

// ---------------- pass B: coarse scatter (LDS cursors) ----------------
__global__ __launch_bounds__(256) void pB_scatter(const int* __restrict__ src,
                                                  const int* __restrict__ dst,
                                                  const int* __restrict__ histT,
                                                  unsigned int* __restrict__ tmp,
                                                  int E, int G) {
    __shared__ int cur[256];
    int g = blockIdx.x, t = threadIdx.x;
    cur[t] = histT[t * G + g];
    __syncthreads();
    int beg = g * EPB, end = min(beg + EPB, E);
    for (int i = beg + t; i < end; i += 256) {
        int d = dst[i], s = src[i];
        int pos = atomicAdd(&cur[d >> 8], 1);
        tmp[pos] = ((unsigned int)(d & 255) << 16) | (unsigned int)(s & 0xFFFF);
    }
}

// ---------------- pass C: per-bucket fine counting sort + CSR metadata -------
__global__ __launch_bounds__(256) void pC_build(const unsigned int* __restrict__ tmp,
                                                const int* __restrict__ coarse,
                                                ushort* __restrict__ csrs,
                                                int* __restrict__ offs,
                                                float* __restrict__ di,
                                                float* __restrict__ dp,
                                                int n, int E, int NB) {
    __shared__ int hist[256];
    __shared__ int cur[256];
    __shared__ int scanbuf[256];
    int b = blockIdx.x, t = threadIdx.x;
    int beg = coarse[b], end = coarse[b + 1];
    hist[t] = 0;
    __syncthreads();
    for (int i = beg + t; i < end; i += 256) atomicAdd(&hist[tmp[i] >> 16], 1);
    __syncthreads();
    int v = hist[t];
    scanbuf[t] = v;
    __syncthreads();
    for (int o = 1; o < 256; o <<= 1) {
        int u = (t >= o) ? scanbuf[t - o] : 0;
        __syncthreads();
        scanbuf[t] += u;
        __syncthreads();
    }
    int excl = scanbuf[t] - v;
    cur[t] = beg + excl;
    int d = (b << 8) + t;
    if (d < n) {
        offs[d] = beg + excl;
        float df = (float)v;
        di[d] = rsqrtf(df + 2.0f);   // improved=True: self-loop weight 2
        dp[d] = rsqrtf(df + 1.0f);   // output layer: improved=False
    }
    if (b == NB - 1 && t == 0) offs[n] = E;
    __syncthreads();
    for (int i = beg + t; i < end; i += 256) {
        unsigned int e = tmp[i];
        int pos = atomicAdd(&cur[e >> 16], 1);
        csrs[pos] = (ushort)(e & 0xFFFFu);
    }
}

// ---- dense GEMM: C[n,64] = di[n] * (A[n,64] @ W[64,64]), C in fp16 ----------
#define GM_BN 128
__global__ __launch_bounds__(256) void k_gemm(const float* __restrict__ A,
                                              const float* __restrict__ W,
                                              const float* __restrict__ di,
                                              __half* __restrict__ C, int n) {
    __shared__ float xT[64][132];
    __shared__ float Wl[64][64];
    int tid = threadIdx.x;
    int nb = blockIdx.x * GM_BN;

    for (int r = 0; r < 4; ++r) {
        int q = tid + 256 * r;
        int row = q >> 4, c4 = (q & 15) << 2;
        *(float4*)&Wl[row][c4] = *(const float4*)&W[row * 64 + c4];
    }
    for (int r = 0; r < 8; ++r) {
        int q = tid + 256 * r;
        int nl = q >> 4, k0 = (q & 15) << 2;
        float4 v = make_float4(0.f, 0.f, 0.f, 0.f);
        if (nb + nl < n) v = *(const float4*)&A[(size_t)(nb + nl) * HF + k0];
        xT[k0 + 0][nl] = v.x; xT[k0 + 1][nl] = v.y;
        xT[k0 + 2][nl] = v.z; xT[k0 + 3][nl] = v.w;
    }
    __syncthreads();

    int tx = tid & 7;
    int ty = tid >> 3;
    int f0 = tx * 8, n0 = ty * 4;
    float acc[4][8];
#pragma unroll
    for (int i = 0; i < 4; ++i)
#pragma unroll
        for (int j = 0; j < 8; ++j) acc[i][j] = 0.f;

#pragma unroll 4
    for (int k = 0; k < 64; ++k) {
        float4 xa = *(float4*)&xT[k][n0];
        float4 wa = *(float4*)&Wl[k][f0];
        float4 wb = *(float4*)&Wl[k][f0 + 4];
        float xs[4] = {xa.x, xa.y, xa.z, xa.w};
        float wsv[8] = {wa.x, wa.y, wa.z, wa.w, wb.x, wb.y, wb.z, wb.w};
#pragma unroll
        for (int i = 0; i < 4; ++i)
#pragma unroll
            for (int j = 0; j < 8; ++j) acc[i][j] += xs[i] * wsv[j];
    }

#pragma unroll
    for (int i = 0; i < 4; ++i) {
        int nn = nb + n0 + i;
        if (nn < n) {
            float dr = di[nn];                  // fold edge weight into table
            union { __half h[8]; float4 f4; } u;
#pragma unroll
            for (int j = 0; j < 8; ++j) u.h[j] = __float2half(acc[i][j] * dr);
            *(float4*)&C[(size_t)nn * HF + f0] = u.f4;
        }
    }
}

// ---------------- agg: one wave per node, half-wave per edge -----------------
// lanes: half = lane>>5 (edge slot), fh = lane&31 (feature pair 2fh,2fh+1)
// returns (a0,a1) = full edge sums for features 2fh, 2fh+1 (both halves valid)
__device__ __forceinline__ void agg_edges2(const __half2* __restrict__ P2,
                                           const ushort* __restrict__ csrs,
                                           int beg, int deg, int half, int fh,
                                           float& A0, float& A1) {
    float a0 = 0.f, a1 = 0.f;
    int pairs = deg >> 1;
    int e = beg + half;
    int chunks = pairs >> 1;
    for (int c = 0; c < chunks; ++c, e += 4) {
        int s0 = csrs[e];
        int s1 = csrs[e + 2];
        float2 v0 = __half22float2(P2[(size_t)s0 * 32 + fh]);
        float2 v1 = __half22float2(P2[(size_t)s1 * 32 + fh]);
        a0 += v0.x; a1 += v0.y;
        a0 += v1.x; a1 += v1.y;
    }
    if (pairs & 1) {
        int s = csrs[e];
        float2 v = __half22float2(P2[(size_t)s * 32 + fh]);
        a0 += v.x; a1 += v.y;
    }
    if ((deg & 1) && half == 0) {
        int s = csrs[beg + deg - 1];
        float2 v = __half22float2(P2[(size_t)s * 32 + fh]);
        a0 += v.x; a1 += v.y;
    }
    a0 += __shfl_xor(a0, 32);
    a1 += __shfl_xor(a1, 32);
    A0 = a0; A1 = a1;
}

__global__ __launch_bounds__(256) void k_agg(const __half2* __restrict__ P2,
                      const int* __restrict__ offs, const ushort* __restrict__ csrs,
                      const float* __restrict__ di, const float* __restrict__ bias,
                      float* __restrict__ out, int n, float fill) {
    int wid = (blockIdx.x * blockDim.x + threadIdx.x) >> 6;
    if (wid >= n) return;
    int lane = threadIdx.x & 63;
    int half = lane >> 5, fh = lane & 31;
    int beg = offs[wid], deg = offs[wid + 1] - beg;
    float a0, a1;
    agg_edges2(P2, csrs, beg, deg, half, fh, a0, a1);
    float dw = di[wid];
    float2 self = __half22float2(P2[(size_t)wid * 32 + fh]);
    a0 = fmaxf(dw * (a0 + fill * self.x) + bias[2 * fh + 0], 0.f);
    a1 = fmaxf(dw * (a1 + fill * self.y) + bias[2 * fh + 1], 0.f);
    if (half == 0)
        *(float2*)&out[(size_t)wid * HF + 2 * fh] = make_float2(a0, a1);
}

// layer-3 agg fused with output projection: z2 = dp * (relu(agg+b) . Wout)
__global__ __launch_bounds__(256) void k_agg_final(const __half2* __restrict__ P2,
                      const int* __restrict__ offs, const ushort* __restrict__ csrs,
                      const float* __restrict__ di, const float* __restrict__ bias,
                      const float* __restrict__ Wout, const float* __restrict__ dp,
                      float* __restrict__ z2, int n) {
    int wid = (blockIdx.x * blockDim.x + threadIdx.x) >> 6;
    if (wid >= n) return;
    int lane = threadIdx.x & 63;
    int half = lane >> 5, fh = lane & 31;
    int beg = offs[wid], deg = offs[wid + 1] - beg;
    float a0, a1;
    agg_edges2(P2, csrs, beg, deg, half, fh, a0, a1);
    float dw = di[wid];
    float2 self = __half22float2(P2[(size_t)wid * 32 + fh]);
    a0 = fmaxf(dw * (a0 + 2.0f * self.x) + bias[2 * fh + 0], 0.f);
    a1 = fmaxf(dw * (a1 + 2.0f * self.y) + bias[2 * fh + 1], 0.f);
    float v = a0 * Wout[2 * fh] + a1 * Wout[2 * fh + 1];
#pragma unroll
    for (int o = 16; o > 0; o >>= 1) v += __shfl_down(v, o, 32);
    if (lane == 0) z2[wid] = v * dp[wid];
}

// out[n] = dp[n] * (sum_e z2[src] + z2[n]) + b_out
__global__ void k_out(const float* __restrict__ z2, const int* __restrict__ offs,
                      const ushort* __restrict__ csrs, const float* __restrict__ dp,
                      const float* __restrict__ bout, float* __restrict__ out, int n) {
    int i = blockIdx.x * blockDim.x + threadIdx.x;
    if (i >= n) return;
    int beg = offs[i], end = offs[i + 1];
    float acc = 0.f;
    for (int e = beg; e < end; ++e) acc += z2[csrs[e]];
    out[i] = dp[i] * (acc + z2[i]) + bout[0];
}

extern "C" void kernel_launch(void* const* d_in, const int* in_sizes, int n_in,
                              void* d_out, int out_size, void* d_ws, size_t ws_size,
                              hipStream_t stream) {
    const float* x    = (const float*)d_in[0];
    const int*   ei   = (const int*)d_in[1];
    const float* W_in = (const float*)d_in[2];
    const float* b_in = (const float*)d_in[3];
    const float* W_h1 = (const float*)d_in[4];
    const float* b_h1 = (const float*)d_in[5];
    const float* W_h2 = (const float*)d_in[6];
    const float* b_h2 = (const float*)d_in[7];
    const float* W_out= (const float*)d_in[8];
    const float* b_out= (const float*)d_in[9];
    float* out = (float*)d_out;

    const int n = in_sizes[0] / HF;        // 50000 (< 65536: ushort CSR ok)
    const int E = in_sizes[1] / 2;         // 1.6M
    const int* src = ei;
    const int* dst = ei + E;

    const int G  = (E + EPB - 1) / EPB;
    const int NB = (n + 255) >> 8;

    char* ws = (char*)d_ws;
    size_t o = 0;
    auto alloc = [&](size_t bytes) -> void* {
        void* p = ws + o;
        o += (bytes + 255) & ~(size_t)255;
        return p;
    };
    int*          offs   = (int*)   alloc((size_t)(n + 1) * 4);
    float*        di     = (float*) alloc((size_t)n * 4);
    float*        dp     = (float*) alloc((size_t)n * 4);
    ushort*       csrs   = (ushort*)alloc((size_t)E * 2);
    unsigned int* tmp    = (unsigned int*)alloc((size_t)E * 4);
    int*          histT  = (int*)   alloc((size_t)G * 256 * 4);
    int*          coarse = (int*)   alloc(257 * 4);
    __half*       hW     = (__half*)alloc((size_t)n * HF * 2);   // fp16 P' table
    float*        hA     = (float*) alloc((size_t)n * HF * 4);
    float*        hB     = (float*) alloc((size_t)n * HF * 4);
    float*        z2     = (float*) alloc((size_t)n * 4);

    const int TB = 256;
    int gbN = (n + TB - 1) / TB;
    int gbW = (n * 64 + TB - 1) / TB;
    int gbG = (n + GM_BN - 1) / GM_BN;

    // ---- CSR build (atomic-free, LDS atomics only) ----
    pA_hist   <<<G,  TB, 0, stream>>>(dst, histT, E, G);
    pScan     <<<1,  ST, 0, stream>>>(histT, coarse, G, E);
    pB_scatter<<<G,  TB, 0, stream>>>(src, dst, histT, tmp, E, G);
    pC_build  <<<NB, TB, 0, stream>>>(tmp, coarse, csrs, offs, di, dp, n, E, NB);

    const __half2* hW2 = (const __half2*)hW;

    // ---- layer 1 ----
    k_gemm<<<gbG, TB, 0, stream>>>(x, W_in, di, hW, n);
    k_agg<<<gbW, TB, 0, stream>>>(hW2, offs, csrs, di, b_in, hA, n, 2.0f);
    // ---- layer 2 ----
    k_gemm<<<gbG, TB, 0, stream>>>(hA, W_h1, di, hW, n);
    k_agg<<<gbW, TB, 0, stream>>>(hW2, offs, csrs, di, b_h1, hB, n, 2.0f);
    // ---- layer 3 (agg fused with output projection) ----
    k_gemm<<<gbG, TB, 0, stream>>>(hB, W_h2, di, hW, n);
    k_agg_final<<<gbW, TB, 0, stream>>>(hW2, offs, csrs, di, b_h2, W_out, dp, z2, n);
    // ---- output layer ----
    k_out<<<gbN, TB, 0, stream>>>(z2, offs, csrs, dp, b_out, out, n);
}